// Round 4
// baseline (178.202 us; speedup 1.0000x reference)
//
#include <hip/hip_runtime.h>

#define NBATCH 16
#define MAXB 256
#define BS 16
#define HQ 32
#define HKV 8
#define G 4
#define HD 128
#define SCALE 0.08838834764831845f
#define NEGF -1.0e30f

__device__ __forceinline__ float dot8(const float4 a0, const float4 a1,
                                      const float4 b0, const float4 b1) {
  return a0.x*b0.x + a0.y*b0.y + a0.z*b0.z + a0.w*b0.w +
         a1.x*b1.x + a1.y*b1.y + a1.z*b1.z + a1.w*b1.w;
}

// Workgroup = (b, split, head-group): 256 threads = 4 waves, wave w owns
// kv-head h = hg*4 + w. Lane layout: tg = lane>>4 (4 positions in flight),
// tl = lane&15 (dims [tl*8, tl*8+8)).
// Double-buffered register page pipeline: load a whole 16-position page of
// K+V (16x16B loads = 64 VGPRs per buffer) one page ahead of compute, so
// ~16-32 loads stay in flight per wave (round 3 had ~4 -> latency-bound at
// 2.3 TB/s effective). ~210 VGPR -> 2 waves/SIMD; no launch_bounds cap
// (r2 lesson: a cap below the live set causes 100MB+ scratch traffic).
__global__ __launch_bounds__(256) void pa_split(
    const float* __restrict__ q,
    const float* __restrict__ knew,
    const float* __restrict__ vnew,
    const float* __restrict__ k_cache,
    const float* __restrict__ v_cache,
    const int* __restrict__ block_tables,
    const int* __restrict__ seq_lens,
    float* __restrict__ part_ml,   // [B][HKV][P][G][2]
    float* __restrict__ part_acc,  // [B][HKV][P][G][HD]
    int nsplit)
{
  const int hg    = blockIdx.x & 1;
  const int split = (blockIdx.x >> 1) % nsplit;
  const int b     = blockIdx.x / (2 * nsplit);
  const int h     = hg * 4 + (threadIdx.x >> 6);
  const int lane  = threadIdx.x & 63;
  const int tg    = lane >> 4;
  const int tl    = lane & 15;

  const int seq_len = seq_lens[b];
  int per = (seq_len + nsplit - 1) / nsplit;
  per = (per + 15) & ~15;             // page-align chunks
  const int s0 = split * per;
  const int s1 = min(seq_len, s0 + per);
  const int last = seq_len - 1;

  float4 q0[G], q1[G];
#pragma unroll
  for (int j = 0; j < G; ++j) {
    const float* qp = q + (size_t)(b*HQ + h*G + j)*HD + tl*8;
    q0[j] = ((const float4*)qp)[0];
    q1[j] = ((const float4*)qp)[1];
  }

  float m[G], l[G];
  float4 a0[G], a1[G];
#pragma unroll
  for (int j = 0; j < G; ++j) {
    m[j] = NEGF; l[j] = 0.f;
    a0[j] = make_float4(0.f,0.f,0.f,0.f);
    a1[j] = make_float4(0.f,0.f,0.f,0.f);
  }

  const float* knp = knew + (size_t)(b*HKV + h)*HD + tl*8;
  const float* vnp = vnew + (size_t)(b*HKV + h)*HD + tl*8;

  auto load_page = [&](float4 (&kr)[4][2], float4 (&vr)[4][2], const int c) {
    const int blk = block_tables[b*MAXB + (c >> 4)];
    const size_t pbase = (size_t)blk*BS*(HKV*HD) + (size_t)h*HD + tl*8;
#pragma unroll
    for (int i = 0; i < 4; ++i) {
      const int s = c + i*4 + tg;
      const float* kp = k_cache + pbase + (size_t)(i*4 + tg)*(HKV*HD);
      const float* vp = v_cache + pbase + (size_t)(i*4 + tg)*(HKV*HD);
      if (s == last) { kp = knp; vp = vnp; }  // token written this step -> k/v inputs
      kr[i][0] = ((const float4*)kp)[0];
      kr[i][1] = ((const float4*)kp)[1];
      vr[i][0] = ((const float4*)vp)[0];
      vr[i][1] = ((const float4*)vp)[1];
    }
  };

  auto compute_page = [&](const float4 (&kr)[4][2], const float4 (&vr)[4][2], const int c) {
#pragma unroll
    for (int i = 0; i < 4; ++i) {
      const int s = c + i*4 + tg;
      const bool valid = s < s1;
      float sc[G];
#pragma unroll
      for (int j = 0; j < G; ++j) {
        float p = dot8(q0[j], q1[j], kr[i][0], kr[i][1]);
        p += __shfl_xor(p, 1, 64);
        p += __shfl_xor(p, 2, 64);
        p += __shfl_xor(p, 4, 64);
        p += __shfl_xor(p, 8, 64);
        sc[j] = valid ? p * SCALE : NEGF;
      }
#pragma unroll
      for (int j = 0; j < G; ++j) {
        const float mn = fmaxf(m[j], sc[j]);
        const float f  = __expf(m[j] - mn);
        const float pp = __expf(sc[j] - mn);
        l[j] = l[j]*f + pp;
        a0[j].x = a0[j].x*f + pp*vr[i][0].x;
        a0[j].y = a0[j].y*f + pp*vr[i][0].y;
        a0[j].z = a0[j].z*f + pp*vr[i][0].z;
        a0[j].w = a0[j].w*f + pp*vr[i][0].w;
        a1[j].x = a1[j].x*f + pp*vr[i][1].x;
        a1[j].y = a1[j].y*f + pp*vr[i][1].y;
        a1[j].z = a1[j].z*f + pp*vr[i][1].z;
        a1[j].w = a1[j].w*f + pp*vr[i][1].w;
        m[j] = mn;
      }
    }
  };

  float4 ka[4][2], va[4][2], kb[4][2], vb[4][2];
  if (s0 < s1) {
    load_page(ka, va, s0);
    for (int c = s0; c < s1; c += 32) {
      if (c + 16 < s1) load_page(kb, vb, c + 16);
      compute_page(ka, va, c);
      if (c + 32 < s1) load_page(ka, va, c + 32);
      if (c + 16 < s1) compute_page(kb, vb, c + 16);
    }
  }

  // combine the 4 tg-subgroup partials (butterfly over xor 16, 32).
  // All-invalid lanes carry m=NEGF -> weight 0.
#pragma unroll
  for (int mask = 16; mask <= 32; mask <<= 1) {
#pragma unroll
    for (int j = 0; j < G; ++j) {
      const float mo = __shfl_xor(m[j], mask, 64);
      const float lo = __shfl_xor(l[j], mask, 64);
      const float mn = fmaxf(m[j], mo);
      const float f0 = __expf(m[j] - mn);
      const float f1 = __expf(mo  - mn);
      l[j] = l[j]*f0 + lo*f1;
      float t;
      t = __shfl_xor(a0[j].x, mask, 64); a0[j].x = a0[j].x*f0 + t*f1;
      t = __shfl_xor(a0[j].y, mask, 64); a0[j].y = a0[j].y*f0 + t*f1;
      t = __shfl_xor(a0[j].z, mask, 64); a0[j].z = a0[j].z*f0 + t*f1;
      t = __shfl_xor(a0[j].w, mask, 64); a0[j].w = a0[j].w*f0 + t*f1;
      t = __shfl_xor(a1[j].x, mask, 64); a1[j].x = a1[j].x*f0 + t*f1;
      t = __shfl_xor(a1[j].y, mask, 64); a1[j].y = a1[j].y*f0 + t*f1;
      t = __shfl_xor(a1[j].z, mask, 64); a1[j].z = a1[j].z*f0 + t*f1;
      t = __shfl_xor(a1[j].w, mask, 64); a1[j].w = a1[j].w*f0 + t*f1;
      m[j] = mn;
    }
  }

  if (tg == 0) {
    const size_t pidx = (size_t)(b*HKV + h)*nsplit + split;
    if (tl == 0) {
#pragma unroll
      for (int j = 0; j < G; ++j) {
        part_ml[(pidx*G + j)*2 + 0] = m[j];
        part_ml[(pidx*G + j)*2 + 1] = l[j];
      }
    }
#pragma unroll
    for (int j = 0; j < G; ++j) {
      float4* ap = (float4*)(part_acc + (pidx*G + j)*HD + tl*8);
      ap[0] = a0[j];
      ap[1] = a1[j];
    }
  }
}

// Reduce: one block per (b, q-head), 128 threads (one per dim).
__global__ __launch_bounds__(128) void pa_reduce(
    const float* __restrict__ part_ml,
    const float* __restrict__ part_acc,
    float* __restrict__ out,
    int P)
{
  const int qh = blockIdx.x % HQ;
  const int b  = blockIdx.x / HQ;
  const int h  = qh >> 2;
  const int j  = qh & 3;
  const int d  = threadIdx.x;

  const size_t base = (size_t)(b*HKV + h) * P;
  float mg = NEGF;
  for (int p = 0; p < P; ++p)
    mg = fmaxf(mg, part_ml[((base + p)*G + j)*2 + 0]);

  float lsum = 0.f, asum = 0.f;
  for (int p = 0; p < P; ++p) {
    const float mm = part_ml[((base + p)*G + j)*2 + 0];
    const float ll = part_ml[((base + p)*G + j)*2 + 1];
    const float f  = __expf(mm - mg);   // empty partial: ll==0, acc==0
    lsum += f * ll;
    asum += f * part_acc[((base + p)*G + j)*HD + d];
  }
  out[(size_t)(b*HQ + qh)*HD + d] = asum / lsum;
}

extern "C" void kernel_launch(void* const* d_in, const int* in_sizes, int n_in,
                              void* d_out, int out_size, void* d_ws, size_t ws_size,
                              hipStream_t stream) {
  const float* q  = (const float*)d_in[0];
  const float* k  = (const float*)d_in[1];
  const float* v  = (const float*)d_in[2];
  const float* kc = (const float*)d_in[3];
  const float* vc = (const float*)d_in[4];
  // d_in[5] = slot_mapping (unused: it addresses logical position seq_len-1)
  const int* bt = (const int*)d_in[6];
  const int* sl = (const int*)d_in[7];
  // d_in[8] = query_lens (all 1), d_in[9] = is_prefill (False) — unused

  int nsplit = 64;
  for (;;) {
    const size_t need = (size_t)NBATCH * HKV * nsplit * G * (2 + HD) * sizeof(float);
    if (need <= ws_size || nsplit == 1) break;
    nsplit >>= 1;
  }
  float* part_ml  = (float*)d_ws;
  float* part_acc = part_ml + (size_t)NBATCH * HKV * nsplit * G * 2;

  hipLaunchKernelGGL(pa_split, dim3(NBATCH * nsplit * 2), dim3(256), 0, stream,
                     q, k, v, kc, vc, bt, sl, part_ml, part_acc, nsplit);
  hipLaunchKernelGGL(pa_reduce, dim3(NBATCH * HQ), dim3(128), 0, stream,
                     part_ml, part_acc, (float*)d_out, nsplit);
}

// Round 5
// 116.987 us; speedup vs baseline: 1.5233x; 1.5233x over previous
//
#include <hip/hip_runtime.h>

#define NBATCH 16
#define MAXB 256
#define BS 16
#define HQ 32
#define HKV 8
#define G 4
#define HD 128
#define SCALE 0.08838834764831845f
#define NEGF -1.0e30f   // running-max init
#define NEGI -2.0e30f   // invalid-position score: exp(NEGI - m) == 0 for any m >= NEGF
#define RESCALE_THR 8.0f

__device__ __forceinline__ float dot8(const float4 a0, const float4 a1,
                                      const float4 b0, const float4 b1) {
  return a0.x*b0.x + a0.y*b0.y + a0.z*b0.z + a0.w*b0.w +
         a1.x*b1.x + a1.y*b1.y + a1.z*b1.z + a1.w*b1.w;
}

// Sum across the 16-lane DPP row (== one tg group) using row_ror adds.
// Pure VALU: replaces 4 __shfl_xor (DS-pipe) per reduction — the DS pipe was
// the measured bottleneck (r1: 24 shfl/pos -> 230us; r3/r4: 16 -> 170us,
// invariant under occupancy and cache level).
template<int CTL>
__device__ __forceinline__ float dpp_row_add(float v) {
  const int s = __builtin_amdgcn_update_dpp(0, __float_as_int(v), CTL, 0xF, 0xF, true);
  return v + __int_as_float(s);
}
__device__ __forceinline__ float row_reduce_add(float v) {
  v = dpp_row_add<0x128>(v);  // row_ror:8
  v = dpp_row_add<0x124>(v);  // row_ror:4
  v = dpp_row_add<0x122>(v);  // row_ror:2
  v = dpp_row_add<0x121>(v);  // row_ror:1
  return v;                   // all 16 lanes of the row hold the sum
}

// Workgroup = (b, split, head-group): 256 threads = 4 waves, wave w owns
// kv-head h = hg*4 + w. Lanes: tg = lane>>4 (4 positions in flight),
// tl = lane&15 (dims [tl*8, tl*8+8)). Single-buffered 16-position page.
__global__ __launch_bounds__(256) void pa_split(
    const float* __restrict__ q,
    const float* __restrict__ knew,
    const float* __restrict__ vnew,
    const float* __restrict__ k_cache,
    const float* __restrict__ v_cache,
    const int* __restrict__ block_tables,
    const int* __restrict__ seq_lens,
    float* __restrict__ part_ml,   // [B][HKV][P][G][2]
    float* __restrict__ part_acc,  // [B][HKV][P][G][HD]
    int nsplit)
{
  const int hg    = blockIdx.x & 1;
  const int split = (blockIdx.x >> 1) % nsplit;
  const int b     = blockIdx.x / (2 * nsplit);
  const int h     = hg * 4 + (threadIdx.x >> 6);
  const int lane  = threadIdx.x & 63;
  const int tg    = lane >> 4;
  const int tl    = lane & 15;

  const int seq_len = seq_lens[b];
  int per = (seq_len + nsplit - 1) / nsplit;
  per = (per + 15) & ~15;             // page-align chunks
  const int s0 = split * per;
  const int s1 = min(seq_len, s0 + per);
  const int last = seq_len - 1;
  const size_t pidx = (size_t)(b*HKV + h)*nsplit + split;

  if (s0 >= seq_len) {
    // inactive split: write a neutral partial (d_ws is not re-poisoned)
    if (tg == 0) {
      if (tl == 0) {
#pragma unroll
        for (int j = 0; j < G; ++j) {
          part_ml[(pidx*G + j)*2 + 0] = NEGF;
          part_ml[(pidx*G + j)*2 + 1] = 0.f;
        }
      }
      const float4 z = make_float4(0.f,0.f,0.f,0.f);
#pragma unroll
      for (int j = 0; j < G; ++j) {
        float4* ap = (float4*)(part_acc + (pidx*G + j)*HD + tl*8);
        ap[0] = z; ap[1] = z;
      }
    }
    return;
  }

  float4 q0[G], q1[G];
#pragma unroll
  for (int j = 0; j < G; ++j) {
    const float* qp = q + (size_t)(b*HQ + h*G + j)*HD + tl*8;
    q0[j] = ((const float4*)qp)[0];
    q1[j] = ((const float4*)qp)[1];
  }

  float m[G], l[G];
  float4 a0[G], a1[G];
#pragma unroll
  for (int j = 0; j < G; ++j) {
    m[j] = NEGF; l[j] = 0.f;
    a0[j] = make_float4(0.f,0.f,0.f,0.f);
    a1[j] = make_float4(0.f,0.f,0.f,0.f);
  }

  const float* knp = knew + (size_t)(b*HKV + h)*HD + tl*8;
  const float* vnp = vnew + (size_t)(b*HKV + h)*HD + tl*8;

  for (int c = s0; c < s1; c += 16) {
    const int blk = block_tables[b*MAXB + (c >> 4)];
    const size_t pbase = (size_t)blk*BS*(HKV*HD) + (size_t)h*HD + tl*8;

    // stage the whole 16-position page (16x16B loads in flight per lane)
    float4 kr[4][2], vr[4][2];
#pragma unroll
    for (int i = 0; i < 4; ++i) {
      const int s = c + i*4 + tg;
      const float* kp = k_cache + pbase + (size_t)(i*4 + tg)*(HKV*HD);
      const float* vp = v_cache + pbase + (size_t)(i*4 + tg)*(HKV*HD);
      if (s == last) { kp = knp; vp = vnp; }  // token written this step -> k/v inputs
      kr[i][0] = ((const float4*)kp)[0];
      kr[i][1] = ((const float4*)kp)[1];
      vr[i][0] = ((const float4*)vp)[0];
      vr[i][1] = ((const float4*)vp)[1];
    }

#pragma unroll
    for (int i = 0; i < 4; ++i) {
      const int s = c + i*4 + tg;
      const bool valid = s < s1;
      float sc[G];
#pragma unroll
      for (int j = 0; j < G; ++j) {
        float p = dot8(q0[j], q1[j], kr[i][0], kr[i][1]);
        p = row_reduce_add(p);                  // VALU-only 16-lane reduce
        sc[j] = valid ? p * SCALE : NEGI;
      }
      // T13 defer-max: rescale only when some score exceeds m + THR.
      // Triggers ~once per stream (first valid position), then ~never.
      bool need = false;
#pragma unroll
      for (int j = 0; j < G; ++j) need = need || (sc[j] > m[j] + RESCALE_THR);
      if (__any(need)) {
#pragma unroll
        for (int j = 0; j < G; ++j) {
          const float mn = fmaxf(m[j], sc[j]);
          const float f  = __expf(m[j] - mn);
          l[j] *= f;
          a0[j].x *= f; a0[j].y *= f; a0[j].z *= f; a0[j].w *= f;
          a1[j].x *= f; a1[j].y *= f; a1[j].z *= f; a1[j].w *= f;
          m[j] = mn;
        }
      }
#pragma unroll
      for (int j = 0; j < G; ++j) {
        const float pp = __expf(sc[j] - m[j]);  // bounded by e^THR; 0 for invalid
        l[j] += pp;
        a0[j].x += pp*vr[i][0].x;
        a0[j].y += pp*vr[i][0].y;
        a0[j].z += pp*vr[i][0].z;
        a0[j].w += pp*vr[i][0].w;
        a1[j].x += pp*vr[i][1].x;
        a1[j].y += pp*vr[i][1].y;
        a1[j].z += pp*vr[i][1].z;
        a1[j].w += pp*vr[i][1].w;
      }
    }
  }

  // combine the 4 tg-subgroup partials (butterfly over xor 16, 32) — once per
  // wave, DS cost negligible. Never-valid rows carry m=NEGF, l=0 -> weight 0.
#pragma unroll
  for (int mask = 16; mask <= 32; mask <<= 1) {
#pragma unroll
    for (int j = 0; j < G; ++j) {
      const float mo = __shfl_xor(m[j], mask, 64);
      const float lo = __shfl_xor(l[j], mask, 64);
      const float mn = fmaxf(m[j], mo);
      const float f0 = __expf(m[j] - mn);
      const float f1 = __expf(mo  - mn);
      l[j] = l[j]*f0 + lo*f1;
      float t;
      t = __shfl_xor(a0[j].x, mask, 64); a0[j].x = a0[j].x*f0 + t*f1;
      t = __shfl_xor(a0[j].y, mask, 64); a0[j].y = a0[j].y*f0 + t*f1;
      t = __shfl_xor(a0[j].z, mask, 64); a0[j].z = a0[j].z*f0 + t*f1;
      t = __shfl_xor(a0[j].w, mask, 64); a0[j].w = a0[j].w*f0 + t*f1;
      t = __shfl_xor(a1[j].x, mask, 64); a1[j].x = a1[j].x*f0 + t*f1;
      t = __shfl_xor(a1[j].y, mask, 64); a1[j].y = a1[j].y*f0 + t*f1;
      t = __shfl_xor(a1[j].z, mask, 64); a1[j].z = a1[j].z*f0 + t*f1;
      t = __shfl_xor(a1[j].w, mask, 64); a1[j].w = a1[j].w*f0 + t*f1;
      m[j] = mn;
    }
  }

  if (tg == 0) {
    if (tl == 0) {
#pragma unroll
      for (int j = 0; j < G; ++j) {
        part_ml[(pidx*G + j)*2 + 0] = m[j];
        part_ml[(pidx*G + j)*2 + 1] = l[j];
      }
    }
#pragma unroll
    for (int j = 0; j < G; ++j) {
      float4* ap = (float4*)(part_acc + (pidx*G + j)*HD + tl*8);
      ap[0] = a0[j];
      ap[1] = a1[j];
    }
  }
}

// Reduce: one block per (b, q-head), 128 threads (one per dim).
__global__ __launch_bounds__(128) void pa_reduce(
    const float* __restrict__ part_ml,
    const float* __restrict__ part_acc,
    float* __restrict__ out,
    int P)
{
  const int qh = blockIdx.x % HQ;
  const int b  = blockIdx.x / HQ;
  const int h  = qh >> 2;
  const int j  = qh & 3;
  const int d  = threadIdx.x;

  const size_t base = (size_t)(b*HKV + h) * P;
  float mg = NEGF;
  for (int p = 0; p < P; ++p)
    mg = fmaxf(mg, part_ml[((base + p)*G + j)*2 + 0]);

  float lsum = 0.f, asum = 0.f;
  for (int p = 0; p < P; ++p) {
    const float mm = part_ml[((base + p)*G + j)*2 + 0];
    const float ll = part_ml[((base + p)*G + j)*2 + 1];
    const float f  = __expf(mm - mg);   // inactive partial: ll==0, acc==0
    lsum += f * ll;
    asum += f * part_acc[((base + p)*G + j)*HD + d];
  }
  out[(size_t)(b*HQ + qh)*HD + d] = asum / lsum;
}

extern "C" void kernel_launch(void* const* d_in, const int* in_sizes, int n_in,
                              void* d_out, int out_size, void* d_ws, size_t ws_size,
                              hipStream_t stream) {
  const float* q  = (const float*)d_in[0];
  const float* k  = (const float*)d_in[1];
  const float* v  = (const float*)d_in[2];
  const float* kc = (const float*)d_in[3];
  const float* vc = (const float*)d_in[4];
  // d_in[5] = slot_mapping (unused: it addresses logical position seq_len-1)
  const int* bt = (const int*)d_in[6];
  const int* sl = (const int*)d_in[7];
  // d_in[8] = query_lens (all 1), d_in[9] = is_prefill (False) — unused

  int nsplit = 64;
  for (;;) {
    const size_t need = (size_t)NBATCH * HKV * nsplit * G * (2 + HD) * sizeof(float);
    if (need <= ws_size || nsplit == 1) break;
    nsplit >>= 1;
  }
  float* part_ml  = (float*)d_ws;
  float* part_acc = part_ml + (size_t)NBATCH * HKV * nsplit * G * 2;

  hipLaunchKernelGGL(pa_split, dim3(NBATCH * nsplit * 2), dim3(256), 0, stream,
                     q, k, v, kc, vc, bt, sl, part_ml, part_acc, nsplit);
  hipLaunchKernelGGL(pa_reduce, dim3(NBATCH * HQ), dim3(128), 0, stream,
                     part_ml, part_acc, (float*)d_out, nsplit);
}

// Round 6
// 106.052 us; speedup vs baseline: 1.6803x; 1.1031x over previous
//
#include <hip/hip_runtime.h>

#define NBATCH 16
#define MAXB 256
#define BS 16
#define HQ 32
#define HKV 8
#define G 4
#define HD 128
#define SCALE 0.08838834764831845f
#define NEGF -1.0e30f   // running-max init
#define NEGI -2.0e30f   // invalid-position score: exp(NEGI - m) == 0 for any m >= NEGF
#define RESCALE_THR 8.0f

__device__ __forceinline__ float dot8(const float4 a0, const float4 a1,
                                      const float4 b0, const float4 b1) {
  return a0.x*b0.x + a0.y*b0.y + a0.z*b0.z + a0.w*b0.w +
         a1.x*b1.x + a1.y*b1.y + a1.z*b1.z + a1.w*b1.w;
}

// Sum across the 16-lane DPP row (== one tg group) using row_ror adds.
// Pure VALU — the DS-pipe shuffle version was the r1-r4 bottleneck.
template<int CTL>
__device__ __forceinline__ float dpp_row_add(float v) {
  const int s = __builtin_amdgcn_update_dpp(0, __float_as_int(v), CTL, 0xF, 0xF, true);
  return v + __int_as_float(s);
}
__device__ __forceinline__ float row_reduce_add(float v) {
  v = dpp_row_add<0x128>(v);  // row_ror:8
  v = dpp_row_add<0x124>(v);  // row_ror:4
  v = dpp_row_add<0x122>(v);  // row_ror:2
  v = dpp_row_add<0x121>(v);  // row_ror:1
  return v;                   // all 16 lanes of the row hold the sum
}

// Workgroup = (b, split, head-group): 256 threads = 4 waves, wave w owns
// kv-head h = hg*4 + w. Lanes: tg = lane>>4 (4 positions in flight),
// tl = lane&15 (dims [tl*8, tl*8+8)).
// Ping-pong double-buffered 16-position pages: page n+1's 32 loads (16 KB/wave)
// stay in flight while page n computes (~800 cy), hiding the ~900-1500 cy
// load latency that r5's single-buffered loop exposed. block_tables entry is
// prefetched one further page ahead so the (scalar) index load never heads
// the chain. ~220 VGPR — same 128-256 occupancy bin as r5's 156 (free).
__global__ __launch_bounds__(256) void pa_split(
    const float* __restrict__ q,
    const float* __restrict__ knew,
    const float* __restrict__ vnew,
    const float* __restrict__ k_cache,
    const float* __restrict__ v_cache,
    const int* __restrict__ block_tables,
    const int* __restrict__ seq_lens,
    float* __restrict__ part_ml,   // [B][HKV][P][G][2]
    float* __restrict__ part_acc,  // [B][HKV][P][G][HD]
    int nsplit)
{
  const int hg    = blockIdx.x & 1;
  const int split = (blockIdx.x >> 1) % nsplit;
  const int b     = blockIdx.x / (2 * nsplit);
  const int h     = hg * 4 + (threadIdx.x >> 6);
  const int lane  = threadIdx.x & 63;
  const int tg    = lane >> 4;
  const int tl    = lane & 15;

  const int seq_len = seq_lens[b];
  int per = (seq_len + nsplit - 1) / nsplit;
  per = (per + 15) & ~15;             // page-align chunks
  const int s0 = split * per;
  const int s1 = min(seq_len, s0 + per);
  const int last = seq_len - 1;
  const size_t pidx = (size_t)(b*HKV + h)*nsplit + split;

  if (s0 >= seq_len) {
    // inactive split: write a neutral partial (d_ws is not re-poisoned)
    if (tg == 0) {
      if (tl == 0) {
#pragma unroll
        for (int j = 0; j < G; ++j) {
          part_ml[(pidx*G + j)*2 + 0] = NEGF;
          part_ml[(pidx*G + j)*2 + 1] = 0.f;
        }
      }
      const float4 z = make_float4(0.f,0.f,0.f,0.f);
#pragma unroll
      for (int j = 0; j < G; ++j) {
        float4* ap = (float4*)(part_acc + (pidx*G + j)*HD + tl*8);
        ap[0] = z; ap[1] = z;
      }
    }
    return;
  }

  float4 q0[G], q1[G];
#pragma unroll
  for (int j = 0; j < G; ++j) {
    const float* qp = q + (size_t)(b*HQ + h*G + j)*HD + tl*8;
    q0[j] = ((const float4*)qp)[0];
    q1[j] = ((const float4*)qp)[1];
  }

  float m[G], l[G];
  float4 a0[G], a1[G];
#pragma unroll
  for (int j = 0; j < G; ++j) {
    m[j] = NEGF; l[j] = 0.f;
    a0[j] = make_float4(0.f,0.f,0.f,0.f);
    a1[j] = make_float4(0.f,0.f,0.f,0.f);
  }

  const float* knp = knew + (size_t)(b*HKV + h)*HD + tl*8;
  const float* vnp = vnew + (size_t)(b*HKV + h)*HD + tl*8;
  const int btbase = b * MAXB;

  auto load_page = [&](float4 (&kr)[4][2], float4 (&vr)[4][2],
                       const int blk, const int c) {
    const size_t pbase = (size_t)blk*BS*(HKV*HD) + (size_t)h*HD + tl*8;
#pragma unroll
    for (int i = 0; i < 4; ++i) {
      const int s = c + i*4 + tg;
      const float* kp = k_cache + pbase + (size_t)(i*4 + tg)*(HKV*HD);
      const float* vp = v_cache + pbase + (size_t)(i*4 + tg)*(HKV*HD);
      if (s == last) { kp = knp; vp = vnp; }  // token written this step -> k/v inputs
      kr[i][0] = ((const float4*)kp)[0];
      kr[i][1] = ((const float4*)kp)[1];
      vr[i][0] = ((const float4*)vp)[0];
      vr[i][1] = ((const float4*)vp)[1];
    }
  };

  auto compute_page = [&](const float4 (&kr)[4][2], const float4 (&vr)[4][2],
                          const int c) {
#pragma unroll
    for (int i = 0; i < 4; ++i) {
      const int s = c + i*4 + tg;
      const bool valid = s < s1;
      float sc[G];
#pragma unroll
      for (int j = 0; j < G; ++j) {
        float p = dot8(q0[j], q1[j], kr[i][0], kr[i][1]);
        p = row_reduce_add(p);                  // VALU-only 16-lane reduce
        sc[j] = valid ? p * SCALE : NEGI;
      }
      // T13 defer-max: rescale only when some score exceeds m + THR.
      bool need = false;
#pragma unroll
      for (int j = 0; j < G; ++j) need = need || (sc[j] > m[j] + RESCALE_THR);
      if (__any(need)) {
#pragma unroll
        for (int j = 0; j < G; ++j) {
          const float mn = fmaxf(m[j], sc[j]);
          const float f  = __expf(m[j] - mn);
          l[j] *= f;
          a0[j].x *= f; a0[j].y *= f; a0[j].z *= f; a0[j].w *= f;
          a1[j].x *= f; a1[j].y *= f; a1[j].z *= f; a1[j].w *= f;
          m[j] = mn;
        }
      }
#pragma unroll
      for (int j = 0; j < G; ++j) {
        const float pp = __expf(sc[j] - m[j]);  // bounded by e^THR; 0 for invalid
        l[j] += pp;
        a0[j].x += pp*vr[i][0].x;
        a0[j].y += pp*vr[i][0].y;
        a0[j].z += pp*vr[i][0].z;
        a0[j].w += pp*vr[i][0].w;
        a1[j].x += pp*vr[i][1].x;
        a1[j].y += pp*vr[i][1].y;
        a1[j].z += pp*vr[i][1].z;
        a1[j].w += pp*vr[i][1].w;
      }
    }
  };

  // ---- ping-pong page pipeline (explicit unroll-by-2, static buffer names) --
  float4 ka[4][2], va[4][2], kb[4][2], vb[4][2];
  int c = s0;
  int blkNext = block_tables[btbase + (c >> 4)];
  load_page(ka, va, blkNext, c);
  if (c + 16 < s1) blkNext = block_tables[btbase + ((c + 16) >> 4)];

  for (;;) {
    // current page in A at position c
    if (c + 16 < s1) {
      load_page(kb, vb, blkNext, c + 16);
      if (c + 32 < s1) blkNext = block_tables[btbase + ((c + 32) >> 4)];
    }
    compute_page(ka, va, c);
    c += 16;
    if (c >= s1) break;

    // current page in B
    if (c + 16 < s1) {
      load_page(ka, va, blkNext, c + 16);
      if (c + 32 < s1) blkNext = block_tables[btbase + ((c + 32) >> 4)];
    }
    compute_page(kb, vb, c);
    c += 16;
    if (c >= s1) break;
  }

  // combine the 4 tg-subgroup partials (butterfly over xor 16, 32) — once per
  // wave, DS cost negligible. Never-valid rows carry m=NEGF, l=0 -> weight 0.
#pragma unroll
  for (int mask = 16; mask <= 32; mask <<= 1) {
#pragma unroll
    for (int j = 0; j < G; ++j) {
      const float mo = __shfl_xor(m[j], mask, 64);
      const float lo = __shfl_xor(l[j], mask, 64);
      const float mn = fmaxf(m[j], mo);
      const float f0 = __expf(m[j] - mn);
      const float f1 = __expf(mo  - mn);
      l[j] = l[j]*f0 + lo*f1;
      float t;
      t = __shfl_xor(a0[j].x, mask, 64); a0[j].x = a0[j].x*f0 + t*f1;
      t = __shfl_xor(a0[j].y, mask, 64); a0[j].y = a0[j].y*f0 + t*f1;
      t = __shfl_xor(a0[j].z, mask, 64); a0[j].z = a0[j].z*f0 + t*f1;
      t = __shfl_xor(a0[j].w, mask, 64); a0[j].w = a0[j].w*f0 + t*f1;
      t = __shfl_xor(a1[j].x, mask, 64); a1[j].x = a1[j].x*f0 + t*f1;
      t = __shfl_xor(a1[j].y, mask, 64); a1[j].y = a1[j].y*f0 + t*f1;
      t = __shfl_xor(a1[j].z, mask, 64); a1[j].z = a1[j].z*f0 + t*f1;
      t = __shfl_xor(a1[j].w, mask, 64); a1[j].w = a1[j].w*f0 + t*f1;
      m[j] = mn;
    }
  }

  if (tg == 0) {
    if (tl == 0) {
#pragma unroll
      for (int j = 0; j < G; ++j) {
        part_ml[(pidx*G + j)*2 + 0] = m[j];
        part_ml[(pidx*G + j)*2 + 1] = l[j];
      }
    }
#pragma unroll
    for (int j = 0; j < G; ++j) {
      float4* ap = (float4*)(part_acc + (pidx*G + j)*HD + tl*8);
      ap[0] = a0[j];
      ap[1] = a1[j];
    }
  }
}

// Reduce: one block per (b, q-head), 128 threads (one per dim).
__global__ __launch_bounds__(128) void pa_reduce(
    const float* __restrict__ part_ml,
    const float* __restrict__ part_acc,
    float* __restrict__ out,
    int P)
{
  const int qh = blockIdx.x % HQ;
  const int b  = blockIdx.x / HQ;
  const int h  = qh >> 2;
  const int j  = qh & 3;
  const int d  = threadIdx.x;

  const size_t base = (size_t)(b*HKV + h) * P;
  float mg = NEGF;
  for (int p = 0; p < P; ++p)
    mg = fmaxf(mg, part_ml[((base + p)*G + j)*2 + 0]);

  float lsum = 0.f, asum = 0.f;
  for (int p = 0; p < P; ++p) {
    const float mm = part_ml[((base + p)*G + j)*2 + 0];
    const float ll = part_ml[((base + p)*G + j)*2 + 1];
    const float f  = __expf(mm - mg);   // inactive partial: ll==0, acc==0
    lsum += f * ll;
    asum += f * part_acc[((base + p)*G + j)*HD + d];
  }
  out[(size_t)(b*HQ + qh)*HD + d] = asum / lsum;
}

extern "C" void kernel_launch(void* const* d_in, const int* in_sizes, int n_in,
                              void* d_out, int out_size, void* d_ws, size_t ws_size,
                              hipStream_t stream) {
  const float* q  = (const float*)d_in[0];
  const float* k  = (const float*)d_in[1];
  const float* v  = (const float*)d_in[2];
  const float* kc = (const float*)d_in[3];
  const float* vc = (const float*)d_in[4];
  // d_in[5] = slot_mapping (unused: it addresses logical position seq_len-1)
  const int* bt = (const int*)d_in[6];
  const int* sl = (const int*)d_in[7];
  // d_in[8] = query_lens (all 1), d_in[9] = is_prefill (False) — unused

  int nsplit = 32;
  for (;;) {
    const size_t need = (size_t)NBATCH * HKV * nsplit * G * (2 + HD) * sizeof(float);
    if (need <= ws_size || nsplit == 1) break;
    nsplit >>= 1;
  }
  float* part_ml  = (float*)d_ws;
  float* part_acc = part_ml + (size_t)NBATCH * HKV * nsplit * G * 2;

  hipLaunchKernelGGL(pa_split, dim3(NBATCH * nsplit * 2), dim3(256), 0, stream,
                     q, k, v, kc, vc, bt, sl, part_ml, part_acc, nsplit);
  hipLaunchKernelGGL(pa_reduce, dim3(NBATCH * HQ), dim3(128), 0, stream,
                     part_ml, part_acc, (float*)d_out, nsplit);
}